// Round 1
// baseline (4839.722 us; speedup 1.0000x reference)
//
#include <hip/hip_runtime.h>
#include <math.h>

#define B_ 32
#define C_ 3
#define H_ 256
#define W_ 832
#define HW_ (H_*W_)
#define K_ 100
#define RPB 16                  // rows per block
#define PARTS (H_/RPB)          // 16 parts per channel
#define NLOAD (W_/4)            // 208 threads carry pixels
#define BLK 256
#define CAP 2048
#define NCAND (C_*PARTS*K_)     // 4800 candidates per batch
#define NB 2048                 // score histogram bins
#define TIE_CAP 128

typedef unsigned long long ull;
struct DetRec { float score; int cls; unsigned hw; };

// Descending bitonic sort of N (power of two) 64-bit keys in LDS (small N only).
template<int N>
__device__ inline void bitonic_sort_desc(ull* s) {
    for (int k = 2; k <= N; k <<= 1) {
        for (int j = k >> 1; j > 0; j >>= 1) {
            __syncthreads();
            for (int i = threadIdx.x; i < N; i += BLK) {
                int ixj = i ^ j;
                if (ixj > i) {
                    ull a = s[i], b = s[ixj];
                    bool up = ((i & k) == 0);
                    if (up ? (a < b) : (a > b)) { s[i] = b; s[ixj] = a; }
                }
            }
        }
    }
    __syncthreads();
}

// Monotone (w.r.t. key order for non-negative scores) score -> bin mapping.
// bin(a) >= bin(b) whenever key a > key b; ties within a bin are resolved
// exactly on the full 64-bit key, so selection stays bit-exact.
__device__ inline int score_bin(ull key) {
    const float v = __uint_as_float((unsigned)(key >> 32));
    return (int)fminf(fmaxf(v * 2048.0f, 0.0f), 2047.0f);
}

// Given hist[NB] (counts per score bin, total >= K), find threshold bin t and
// kneed = K - (#keys in bins > t). Shuffle-based suffix scan: 2 barriers total.
// Writes results to *t_s / *kneed_s (shared); all threads see them on return.
__device__ inline void find_threshold(const unsigned* __restrict__ hist,
                                      unsigned* __restrict__ wtot,
                                      int* __restrict__ t_s,
                                      int* __restrict__ kneed_s) {
    const int tid = threadIdx.x;
    const int lane = tid & 63;
    const int wid = tid >> 6;
    unsigned l[8];
    unsigned Ls = 0;
    #pragma unroll
    for (int j = 0; j < 8; ++j) { l[j] = hist[tid * 8 + j]; Ls += l[j]; }
    // intra-wave inclusive suffix scan of per-thread totals
    unsigned x = Ls;
    #pragma unroll
    for (int off = 1; off < 64; off <<= 1) {
        unsigned y = __shfl_down(x, off);
        if (lane + off < 64) x += y;
    }
    if (lane == 0) wtot[wid] = x;   // wave totals
    __syncthreads();
    unsigned tail = 0;
    #pragma unroll
    for (int w = 0; w < 4; ++w) if (w > wid) tail += wtot[w];
    // s = S(first bin of thread tid+1) ; S(b) = #keys with bin >= b
    unsigned s = x - Ls + tail;
    #pragma unroll
    for (int j = 7; j >= 0; --j) {
        const unsigned Sj = s + l[j];
        if (Sj >= (unsigned)K_ && s < (unsigned)K_) {  // unique crossing thread
            *t_s = tid * 8 + j;
            *kneed_s = K_ - (int)s;
        }
        s = Sj;
    }
    __syncthreads();
}

// ---------------------------------------------------------------------------
// Kernel 1: separable 3x3 peak detect + exact top-100 per (channel, 16-row
// part). key = (value_bits<<32) | ~((c<<18)|pixel): unified comparator
// (score desc, channel asc, pixel asc) == composed jax two-stage top_k.
// Selection: single-shot 2048-bin score histogram + shuffle suffix scan
// (replaces 8-pass radix select: ~150 barriers -> ~8). Exact tie handling
// on the threshold bin via full-key ranks. Output: unsorted top-100 set.
// ---------------------------------------------------------------------------
union TopkShared {
    float vm[2][W_];        // 6656 B — live only during the row loop
    unsigned hist[NB];      // 8192 B — live only after the row loop
};

__global__ void __launch_bounds__(BLK) topk_part_kernel(
        const float* __restrict__ heat, ull* __restrict__ part_out) {
    const int chan = blockIdx.x / PARTS;   // b*C + c
    const int c    = chan % C_;
    const int part = blockIdx.x % PARTS;
    const float* __restrict__ hp = heat + (size_t)chan * HW_;
    const int r0 = part * RPB;
    const int tid = threadIdx.x;
    const bool active = tid < NLOAD;
    const int x4 = tid * 4;
    const int lane = tid & 63;

    __shared__ TopkShared sh;
    __shared__ ull buf[CAP];
    __shared__ ull tie[TIE_CAP];
    __shared__ unsigned wtot[4];
    __shared__ int cnt, ocnt, tcnt, t_s, kneed_s;
    if (tid == 0) cnt = 0;

    float4 rA, rB, rC, rD;
    if (active) {
        const int ym1 = (r0 == 0) ? 0 : r0 - 1;
        rA = reinterpret_cast<const float4*>(hp + (size_t)ym1 * W_)[tid];
        rB = reinterpret_cast<const float4*>(hp + (size_t)r0  * W_)[tid];
        const int yp1 = (r0 == H_ - 1) ? r0 : r0 + 1;
        rC = reinterpret_cast<const float4*>(hp + (size_t)yp1 * W_)[tid];
    }
    __syncthreads();   // cnt=0 visible

    for (int r = 0; r < RPB; ++r) {
        const int y = r0 + r;
        float* vr = sh.vm[r & 1];
        float4 vm;
        if (active) {
            // prefetch row y+2 (clamped) for next round — overlaps with LDS work
            const int yn = (y + 2 > H_ - 1) ? H_ - 1 : y + 2;
            rD = reinterpret_cast<const float4*>(hp + (size_t)yn * W_)[tid];
            vm.x = fmaxf(fmaxf(rA.x, rB.x), rC.x);
            vm.y = fmaxf(fmaxf(rA.y, rB.y), rC.y);
            vm.z = fmaxf(fmaxf(rA.z, rB.z), rC.z);
            vm.w = fmaxf(fmaxf(rA.w, rB.w), rC.w);
            reinterpret_cast<float4*>(&vr[x4])[0] = vm;
        }
        __syncthreads();   // single barrier per row (double-buffered vmrow)
        {
            float left = -INFINITY, right = -INFINITY;
            float vv0 = 0.f, vv1 = 0.f, vv2 = 0.f, vv3 = 0.f;
            if (active) {
                left  = (tid == 0)         ? -INFINITY : vr[x4 - 1];
                right = (tid == NLOAD - 1) ? -INFINITY : vr[x4 + 4];
                vv0 = rB.x; vv1 = rB.y; vv2 = rB.z; vv3 = rB.w;
            }
            const float vn[6] = {left, vm.x, vm.y, vm.z, vm.w, right};
            const float vv[4] = {vv0, vv1, vv2, vv3};
            #pragma unroll
            for (int i = 0; i < 4; ++i) {
                const float v = vv[i];
                const bool peak = active && (v >= vn[i]) && (v >= vn[i+1]) && (v >= vn[i+2]);
                const ull m = __ballot(peak);
                if (peak) {
                    const unsigned p = (unsigned)(y * W_ + x4 + i);
                    const unsigned tiek = ((unsigned)c << 18) | p;
                    const ull key = ((ull)__float_as_uint(v) << 32) | (ull)(~tiek);
                    const int rank = __popcll(m & ((1ULL << lane) - 1ULL));
                    const int leader = __ffsll((long long)m) - 1;
                    int base = 0;
                    if (lane == leader) base = atomicAdd(&cnt, (int)__popcll(m));
                    base = __shfl(base, leader);
                    const int pos = base + rank;
                    if (pos < CAP) buf[pos] = key;
                }
            }
        }
        rA = rB; rB = rC; rC = rD;
    }
    __syncthreads();   // cnt + buf final; sh.vm dead from here on

    const int cc = (cnt < CAP) ? cnt : CAP;
    ull* o = part_out + (size_t)blockIdx.x * K_;

    if (cc <= K_) {    // uniform branch — fewer candidates than K: emit all
        for (int i = tid; i < cc; i += BLK) o[i] = buf[i];
        for (int i = cc + tid; i < K_; i += BLK) o[i] = 0ULL;
        return;
    }

    // 1. zero histogram (aliases vm buffers) + counters
    #pragma unroll
    for (int j = 0; j < NB / BLK; ++j) sh.hist[tid + j * BLK] = 0u;
    if (tid == 0) { ocnt = 0; tcnt = 0; }
    __syncthreads();

    // 2. one-shot histogram over score bins
    for (int i = tid; i < cc; i += BLK) atomicAdd(&sh.hist[score_bin(buf[i])], 1u);
    __syncthreads();

    // 3. threshold bin + kneed via shuffle suffix scan
    find_threshold(sh.hist, wtot, &t_s, &kneed_s);
    const int t = t_s, kneed = kneed_s, n1 = K_ - kneed;

    // 4. emit bins > t directly; collect threshold-bin ties
    for (int i = tid; i < cc; i += BLK) {
        const ull key = buf[i];
        const int bn = score_bin(key);
        if (bn > t) {
            o[atomicAdd(&ocnt, 1)] = key;           // exactly n1 of these
        } else if (bn == t) {
            const int p = atomicAdd(&tcnt, 1);
            if (p < TIE_CAP) tie[p] = key;
        }
    }
    __syncthreads();

    // 5. exact full-key rank among ties; slot n1+r (keys unique -> ranks unique)
    const int m = tcnt;
    if (m <= TIE_CAP) {
        for (int i = tid; i < m; i += BLK) {
            const ull key = tie[i];
            int r = 0;
            for (int j = 0; j < m; ++j) r += (tie[j] > key) ? 1 : 0;
            if (r < kneed) o[n1 + r] = key;
        }
    } else {
        // pathological fallback (tie bin overflow): exact scan over buf
        for (int i = tid; i < cc; i += BLK) {
            const ull key = buf[i];
            if (score_bin(key) != t) continue;
            int r = 0;
            for (int j = 0; j < cc; ++j) {
                const ull kj = buf[j];
                r += (score_bin(kj) == t && kj > key) ? 1 : 0;
            }
            if (r < kneed) o[n1 + r] = key;
        }
    }
    // slots [0,n1) + {n1+r | r<kneed} cover all K_ outputs exactly — no pad.
}

// ---------------------------------------------------------------------------
// Kernel 2: per-batch top-100 of 48x100 candidates. Same one-shot histogram
// select (replaces 8-pass radix), then tiny sort-128, emit rank-ordered DetRec.
// ---------------------------------------------------------------------------
__global__ void __launch_bounds__(BLK) merge_kernel(
        const ull* __restrict__ part_keys, DetRec* __restrict__ dets) {
    const int b = blockIdx.x;
    const int tid = threadIdx.x;
    __shared__ ull buf[NCAND];
    __shared__ unsigned hist[NB];
    __shared__ ull sel[128];
    __shared__ ull tie[TIE_CAP];
    __shared__ unsigned wtot[4];
    __shared__ int ocnt, tcnt, t_s, kneed_s;
    const ull* src = part_keys + (size_t)b * NCAND;
    for (int i = tid; i < NCAND; i += BLK) buf[i] = src[i];
    #pragma unroll
    for (int j = 0; j < NB / BLK; ++j) hist[tid + j * BLK] = 0u;
    if (tid < 128) sel[tid] = 0ULL;
    if (tid == 0) { ocnt = 0; tcnt = 0; }
    __syncthreads();

    for (int i = tid; i < NCAND; i += BLK) atomicAdd(&hist[score_bin(buf[i])], 1u);
    __syncthreads();

    find_threshold(hist, wtot, &t_s, &kneed_s);
    const int t = t_s, kneed = kneed_s, n1 = K_ - kneed;

    for (int i = tid; i < NCAND; i += BLK) {
        const ull key = buf[i];
        const int bn = score_bin(key);
        if (bn > t) {
            sel[atomicAdd(&ocnt, 1)] = key;         // exactly n1 < K_ of these
        } else if (bn == t) {
            const int p = atomicAdd(&tcnt, 1);
            if (p < TIE_CAP) tie[p] = key;
        }
    }
    __syncthreads();

    const int m = tcnt;
    if (m <= TIE_CAP) {
        for (int i = tid; i < m; i += BLK) {
            const ull key = tie[i];
            int r = 0;
            for (int j = 0; j < m; ++j) r += (tie[j] > key) ? 1 : 0;
            // duplicate pad keys (0) share a rank and collapse to one slot —
            // remaining slots stay 0 (pre-zeroed sel), which is exactly right.
            if (r < kneed) sel[n1 + r] = key;
        }
    } else {
        for (int i = tid; i < NCAND; i += BLK) {
            const ull key = buf[i];
            if (score_bin(key) != t) continue;
            int r = 0;
            for (int j = 0; j < NCAND; ++j) {
                const ull kj = buf[j];
                r += (score_bin(kj) == t && kj > key) ? 1 : 0;
            }
            if (r < kneed) sel[n1 + r] = key;
        }
    }
    bitonic_sort_desc<128>(sel);   // has leading __syncthreads

    for (int i = tid; i < K_; i += BLK) {
        const ull key = sel[i];
        const unsigned tiek = ~(unsigned)(key & 0xFFFFFFFFULL);
        DetRec d;
        d.score = __uint_as_float((unsigned)(key >> 32));
        d.cls   = (int)((tiek >> 18) & 3u);
        d.hw    = tiek & 0x3FFFFu;          // >= HW_ only for pad keys (score 0)
        dets[(size_t)b * K_ + i] = d;
    }
}

// ---------------------------------------------------------------------------
// Kernel 3: per-detection geometry (3200 threads).
// ---------------------------------------------------------------------------
__global__ void __launch_bounds__(BLK) geom_kernel(
        const DetRec* __restrict__ dets, const float* __restrict__ reg,
        const float* __restrict__ trans, const float* __restrict__ Km,
        const float* __restrict__ sz, const float* __restrict__ hcam,
        const float* __restrict__ dimen, float* __restrict__ out) {
    const int n = blockIdx.x * blockDim.x + threadIdx.x;
    if (n >= B_ * K_) return;
    const int b = n / K_;
    DetRec d = dets[n];
    const float score = d.score;
    const float clsf = (float)d.cls;
    unsigned hw = d.hw; if (hw >= HW_) hw = 0;  // pad entries: score==0, row zeroed
    const float xs = (float)(hw % W_);
    const float ys = (float)(hw / W_);

    const float* rg = reg + (size_t)b * 4 * HW_;
    const float delta = rg[hw];
    const float off_u = rg[HW_ + hw];
    const float ori0  = rg[2 * HW_ + hw];
    const float ori1  = rg[3 * HW_ + hw];

    const float* T = trans + b * 9;
    const float t00=T[0], t01=T[1], t02=T[2], t10=T[3], t11=T[4], t12=T[5],
                t20=T[6], t21=T[7], t22=T[8];
    const float det3 = t00*(t11*t22 - t12*t21) - t01*(t10*t22 - t12*t20)
                     + t02*(t10*t21 - t11*t20);
    const float idt = 1.0f / det3;
    const float i00 = (t11*t22 - t12*t21)*idt;
    const float i01 = (t02*t21 - t01*t22)*idt;
    const float i02 = (t01*t12 - t02*t11)*idt;

    const float pu = xs + off_u;
    const float img_x = i00*pu + i01*ys + i02;

    const float* Kb = Km + b * 9;
    const float k00=Kb[0],k01=Kb[1],k02=Kb[2],k10=Kb[3],k11=Kb[4],k12=Kb[5],
                k20=Kb[6],k21=Kb[7],k22=Kb[8];
    const float fx = k00, fy = k11, cx = k02;
    const float h = hcam[b];
    float d0 = dimen[b*3+0], d1 = dimen[b*3+1], d2 = dimen[b*3+2];
    if (!isfinite(d0)) d0 = 3.88f;
    if (!isfinite(d1)) d1 = 1.63f;
    if (!isfinite(d2)) d2 = 1.53f;

    const float h_ref = h - d1 * 0.5f;
    const float fyh = fy * fabsf(h_ref);
    const float log_dv_ref = logf(fmaxf(fyh, 1e-7f) / 28.01f);
    const float log_dv = fminf(fmaxf(log_dv_ref + delta, -4.0f), 8.0f);
    const float depth = fminf(fmaxf(fyh * expf(-log_dv), 0.5f), 120.0f);
    const float px = (img_x - cx) * depth / fx;

    const float PI_F  = 3.14159265358979323846f;
    const float ray = atanf(px / (depth + 1e-7f));
    float alpha = atanf(ori0 / (ori1 + 1e-7f));
    alpha += (ori1 >= 0.0f) ? -1.5707963267948966f : 1.5707963267948966f;
    float roty = alpha + ray;
    if (roty >  PI_F) roty -= 6.283185307179586f;
    if (roty < -PI_F) roty += 6.283185307179586f;

    const float cosr = cosf(roty), sinr = sinf(roty);
    const float cx8[8] = {-0.5f, 0.5f, 0.5f, 0.5f, 0.5f,-0.5f,-0.5f,-0.5f};
    const float cy8[8] = {-1.0f,-1.0f, 0.0f, 0.0f,-1.0f,-1.0f, 0.0f, 0.0f};
    const float cz8[8] = {-0.5f,-0.5f,-0.5f, 0.5f, 0.5f, 0.5f, 0.5f,-0.5f};
    float umin = 1e30f, umax = -1e30f, vmin = 1e30f, vmax = -1e30f;
    #pragma unroll
    for (int i = 0; i < 8; ++i) {
        const float xc = d0 * cx8[i];
        const float yc = d1 * cy8[i];
        const float zc = d2 * cz8[i];
        const float X = cosr*xc + sinr*zc + px;
        const float Y = yc + h;
        const float Z = -sinr*xc + cosr*zc + depth;
        const float w = k20*X + k21*Y + k22*Z;
        const float u = (k00*X + k01*Y + k02*Z) / w;
        const float v = (k10*X + k11*Y + k12*Z) / w;
        umin = fminf(umin, u); umax = fmaxf(umax, u);
        vmin = fminf(vmin, v); vmax = fmaxf(vmax, v);
    }
    const float img_w = sz[0], img_h = sz[1];
    const float xmin = fminf(fmaxf(umin, 0.0f), img_w);
    const float xmax = fminf(fmaxf(umax, 0.0f), img_w);
    const float ymin = fminf(fmaxf(vmin, 0.0f), img_h);
    const float ymax = fminf(fmaxf(vmax, 0.0f), img_h);

    const float keep = (score > 0.25f) ? 1.0f : 0.0f;
    float* o = out + (size_t)n * 14;
    o[0]  = clsf  * keep;
    o[1]  = alpha * keep;
    o[2]  = xmin  * keep;
    o[3]  = ymin  * keep;
    o[4]  = xmax  * keep;
    o[5]  = ymax  * keep;
    o[6]  = d1    * keep;   // pred_dims = roll(dims,-1)
    o[7]  = d2    * keep;
    o[8]  = d0    * keep;
    o[9]  = px    * keep;
    o[10] = h     * keep;
    o[11] = depth * keep;
    o[12] = roty  * keep;
    o[13] = score * keep;
}

extern "C" void kernel_launch(void* const* d_in, const int* in_sizes, int n_in,
                              void* d_out, int out_size, void* d_ws, size_t ws_size,
                              hipStream_t stream) {
    const float* heat  = (const float*)d_in[0];  // (32,3,256,832)
    const float* reg   = (const float*)d_in[1];  // (32,4,256,832)
    const float* trans = (const float*)d_in[2];  // (32,3,3)
    const float* Kmat  = (const float*)d_in[3];  // (32,3,3)
    const float* sz    = (const float*)d_in[4];  // (32,2)
    const float* hcam  = (const float*)d_in[5];  // (32,)
    const float* dimen = (const float*)d_in[6];  // (32,3)
    float* out = (float*)d_out;

    char* ws = (char*)d_ws;
    ull* part_keys = (ull*)ws;                                    // 1536*100*8 = 1,228,800 B
    ws += (size_t)B_ * C_ * PARTS * K_ * sizeof(ull);
    DetRec* dets = (DetRec*)ws;                                   // 3200*12 = 38,400 B

    topk_part_kernel<<<B_ * C_ * PARTS, BLK, 0, stream>>>(heat, part_keys);
    merge_kernel<<<B_, BLK, 0, stream>>>(part_keys, dets);
    geom_kernel<<<(B_ * K_ + BLK - 1) / BLK, BLK, 0, stream>>>(
        dets, reg, trans, Kmat, sz, hcam, dimen, out);
}

// Round 2
// 245.045 us; speedup vs baseline: 19.7503x; 19.7503x over previous
//
#include <hip/hip_runtime.h>
#include <math.h>

#define B_ 32
#define C_ 3
#define H_ 256
#define W_ 832
#define HW_ (H_*W_)
#define K_ 100
#define RPB 16                  // rows per block
#define PARTS (H_/RPB)          // 16 parts per channel
#define NLOAD (W_/4)            // 208 threads carry pixels
#define BLK 256
#define CAP 2048
#define NCAND (C_*PARTS*K_)     // 4800 candidates per batch
#define NB 2048                 // radix digit bins (11 bits)
#define TIE_CAP 128
#define SEL_PASSES 6

typedef unsigned long long ull;
struct DetRec { float score; int cls; unsigned hw; };

// Descending bitonic sort of N (power of two) 64-bit keys in LDS (small N only).
template<int N>
__device__ inline void bitonic_sort_desc(ull* s) {
    for (int k = 2; k <= N; k <<= 1) {
        for (int j = k >> 1; j > 0; j >>= 1) {
            __syncthreads();
            for (int i = threadIdx.x; i < N; i += BLK) {
                int ixj = i ^ j;
                if (ixj > i) {
                    ull a = s[i], b = s[ixj];
                    bool up = ((i & k) == 0);
                    if (up ? (a < b) : (a > b)) { s[i] = b; s[ixj] = a; }
                }
            }
        }
    }
    __syncthreads();
}

// Given hist[NB] (digit counts, group total >= kneed), find digit d where the
// suffix count crosses kneed. Shuffle-based suffix scan, 2 barriers.
// Outputs (all threads see them on return): d, krem = kneed - (#keys with
// digit > d), m = count at digit d.
__device__ inline void find_digit(const unsigned* __restrict__ hist,
                                  unsigned* __restrict__ wtot,
                                  const int kneed,
                                  int* __restrict__ d_s,
                                  int* __restrict__ krem_s,
                                  int* __restrict__ m_s) {
    const int tid = threadIdx.x;
    const int lane = tid & 63;
    const int wid = tid >> 6;
    unsigned l[8];
    unsigned Ls = 0;
    #pragma unroll
    for (int j = 0; j < 8; ++j) { l[j] = hist[tid * 8 + j]; Ls += l[j]; }
    // intra-wave inclusive suffix scan of per-thread totals
    unsigned x = Ls;
    #pragma unroll
    for (int off = 1; off < 64; off <<= 1) {
        unsigned y = __shfl_down(x, off);
        if (lane + off < 64) x += y;
    }
    if (lane == 0) wtot[wid] = x;   // wave totals
    __syncthreads();
    unsigned tail = 0;
    #pragma unroll
    for (int w = 0; w < 4; ++w) if (w > wid) tail += wtot[w];
    // s = count of keys in digits strictly above this thread's digit range
    unsigned s = x - Ls + tail;
    #pragma unroll
    for (int j = 7; j >= 0; --j) {
        const unsigned Sj = s + l[j];
        if (Sj >= (unsigned)kneed && s < (unsigned)kneed) {  // unique thread
            *d_s = tid * 8 + j;
            *krem_s = kneed - (int)s;
            *m_s = (int)l[j];
        }
        s = Sj;
    }
    __syncthreads();
}

// ---------------------------------------------------------------------------
// Exact top-K_ select from buf[0..cnt) (cnt >= K_) into dst[0..K_) (unsorted).
// MSB-first 2048-way radix over the 64-bit key with early exit: as soon as the
// threshold digit group fits TIE_CAP, rank its members exactly on the full key
// (O(m^2), m small). Distribution-robust: each pass descends into exactly the
// bits where surviving keys differ (fixes the round-1 pathology where value
// bins collapsed for scores concentrated near 1.0). Distinct keys cannot
// survive 6 passes; an all-identical group (zero pads only) is special-cased.
// sh: int[5] shared scratch {ocnt, tcnt, d, krem, m}.
// ---------------------------------------------------------------------------
__device__ inline void select_topk(const ull* __restrict__ buf, const int cnt,
                                   ull* __restrict__ dst,
                                   unsigned* __restrict__ hist,
                                   ull* __restrict__ tie,
                                   unsigned* __restrict__ wtot,
                                   int* __restrict__ sh) {
    const int tid = threadIdx.x;
    if (tid == 0) sh[0] = 0;                 // ocnt (published by pass-0 barriers)
    int kneed = K_;
    int pshift = 0;                          // valid for pass > 0
    ull prefix = 0;
    for (int pass = 0; pass < SEL_PASSES; ++pass) {
        const int rs = 53 - 11 * pass;
        const int shift = (rs > 0) ? rs : 0;
        #pragma unroll
        for (int j = 0; j < NB / BLK; ++j) hist[tid + j * BLK] = 0u;
        if (tid == 0) sh[1] = 0;             // tcnt
        __syncthreads();
        for (int i = tid; i < cnt; i += BLK) {
            const ull key = buf[i];
            if (pass > 0 && (key >> pshift) != prefix) continue;
            atomicAdd(&hist[(unsigned)(key >> shift) & 2047u], 1u);
        }
        __syncthreads();
        find_digit(hist, wtot, kneed, &sh[2], &sh[3], &sh[4]);
        const int d = sh[2], krem = sh[3], m = sh[4];
        const bool last = (m <= TIE_CAP) || (pass == SEL_PASSES - 1);
        // emit digits > d (they are certainly in the top-K); on the final pass
        // also collect the threshold group for exact ranking
        for (int i = tid; i < cnt; i += BLK) {
            const ull key = buf[i];
            if (pass > 0 && (key >> pshift) != prefix) continue;
            const int dg = (int)((unsigned)(key >> shift) & 2047u);
            if (dg > d) {
                dst[atomicAdd(&sh[0], 1)] = key;
            } else if (last && dg == d) {
                const int p = atomicAdd(&sh[1], 1);
                if (p < TIE_CAP) tie[p] = key;
            }
        }
        __syncthreads();
        if (last) {
            const int n1 = K_ - krem;
            if (sh[1] <= TIE_CAP) {
                const int mm = sh[1];
                for (int i = tid; i < mm; i += BLK) {
                    const ull key = tie[i];
                    int r = 0;
                    for (int j = 0; j < mm; ++j) r += (tie[j] > key) ? 1 : 0;
                    if (r < krem) dst[n1 + r] = key;   // distinct keys -> unique ranks
                }
            } else {
                // >TIE_CAP keys identical in all 64 bits: only possible for pad
                // keys; emit copies
                for (int i = tid; i < krem; i += BLK) dst[n1 + i] = tie[0];
            }
            __syncthreads();
            return;
        }
        prefix = (prefix << 11) | (ull)(unsigned)d;
        pshift = shift;
        kneed = krem;
    }
}

// ---------------------------------------------------------------------------
// Kernel 1: separable 3x3 peak detect + exact top-100 per (channel, 16-row
// part). key = (value_bits<<32) | ~((c<<18)|pixel): unified comparator
// (score desc, channel asc, pixel asc) == composed jax two-stage top_k.
// Output: unsorted top-100 set.
// ---------------------------------------------------------------------------
union TopkShared {
    float vm[2][W_];        // 6656 B — live only during the row loop
    unsigned hist[NB];      // 8192 B — live only after the row loop
};

__global__ void __launch_bounds__(BLK) topk_part_kernel(
        const float* __restrict__ heat, ull* __restrict__ part_out) {
    const int chan = blockIdx.x / PARTS;   // b*C + c
    const int c    = chan % C_;
    const int part = blockIdx.x % PARTS;
    const float* __restrict__ hp = heat + (size_t)chan * HW_;
    const int r0 = part * RPB;
    const int tid = threadIdx.x;
    const bool active = tid < NLOAD;
    const int x4 = tid * 4;
    const int lane = tid & 63;

    __shared__ TopkShared sh;
    __shared__ ull buf[CAP];
    __shared__ ull tie[TIE_CAP];
    __shared__ unsigned wtot[4];
    __shared__ int cnt;
    __shared__ int selsh[5];
    if (tid == 0) cnt = 0;

    float4 rA, rB, rC, rD;
    if (active) {
        const int ym1 = (r0 == 0) ? 0 : r0 - 1;
        rA = reinterpret_cast<const float4*>(hp + (size_t)ym1 * W_)[tid];
        rB = reinterpret_cast<const float4*>(hp + (size_t)r0  * W_)[tid];
        const int yp1 = (r0 == H_ - 1) ? r0 : r0 + 1;
        rC = reinterpret_cast<const float4*>(hp + (size_t)yp1 * W_)[tid];
    }
    __syncthreads();   // cnt=0 visible

    for (int r = 0; r < RPB; ++r) {
        const int y = r0 + r;
        float* vr = sh.vm[r & 1];
        float4 vm;
        if (active) {
            // prefetch row y+2 (clamped) for next round — overlaps with LDS work
            const int yn = (y + 2 > H_ - 1) ? H_ - 1 : y + 2;
            rD = reinterpret_cast<const float4*>(hp + (size_t)yn * W_)[tid];
            vm.x = fmaxf(fmaxf(rA.x, rB.x), rC.x);
            vm.y = fmaxf(fmaxf(rA.y, rB.y), rC.y);
            vm.z = fmaxf(fmaxf(rA.z, rB.z), rC.z);
            vm.w = fmaxf(fmaxf(rA.w, rB.w), rC.w);
            reinterpret_cast<float4*>(&vr[x4])[0] = vm;
        }
        __syncthreads();   // single barrier per row (double-buffered vmrow)
        {
            float left = -INFINITY, right = -INFINITY;
            float vv0 = 0.f, vv1 = 0.f, vv2 = 0.f, vv3 = 0.f;
            if (active) {
                left  = (tid == 0)         ? -INFINITY : vr[x4 - 1];
                right = (tid == NLOAD - 1) ? -INFINITY : vr[x4 + 4];
                vv0 = rB.x; vv1 = rB.y; vv2 = rB.z; vv3 = rB.w;
            }
            const float vn[6] = {left, vm.x, vm.y, vm.z, vm.w, right};
            const float vv[4] = {vv0, vv1, vv2, vv3};
            #pragma unroll
            for (int i = 0; i < 4; ++i) {
                const float v = vv[i];
                const bool peak = active && (v >= vn[i]) && (v >= vn[i+1]) && (v >= vn[i+2]);
                const ull m = __ballot(peak);
                if (peak) {
                    const unsigned p = (unsigned)(y * W_ + x4 + i);
                    const unsigned tiek = ((unsigned)c << 18) | p;
                    const ull key = ((ull)__float_as_uint(v) << 32) | (ull)(~tiek);
                    const int rank = __popcll(m & ((1ULL << lane) - 1ULL));
                    const int leader = __ffsll((long long)m) - 1;
                    int base = 0;
                    if (lane == leader) base = atomicAdd(&cnt, (int)__popcll(m));
                    base = __shfl(base, leader);
                    const int pos = base + rank;
                    if (pos < CAP) buf[pos] = key;
                }
            }
        }
        rA = rB; rB = rC; rC = rD;
    }
    __syncthreads();   // cnt + buf final; sh.vm dead from here on

    const int cc = (cnt < CAP) ? cnt : CAP;
    ull* o = part_out + (size_t)blockIdx.x * K_;

    if (cc <= K_) {    // uniform branch — fewer candidates than K: emit all
        for (int i = tid; i < cc; i += BLK) o[i] = buf[i];
        for (int i = cc + tid; i < K_; i += BLK) o[i] = 0ULL;
        return;
    }

    select_topk(buf, cc, o, sh.hist, tie, wtot, selsh);
}

// ---------------------------------------------------------------------------
// Kernel 2: per-batch top-100 of 48x100 candidates (radix-with-early-exit
// select), then tiny sort-128, emit rank-ordered DetRec.
// ---------------------------------------------------------------------------
__global__ void __launch_bounds__(BLK) merge_kernel(
        const ull* __restrict__ part_keys, DetRec* __restrict__ dets) {
    const int b = blockIdx.x;
    const int tid = threadIdx.x;
    __shared__ ull buf[NCAND];
    __shared__ unsigned hist[NB];
    __shared__ ull sel[128];
    __shared__ ull tie[TIE_CAP];
    __shared__ unsigned wtot[4];
    __shared__ int selsh[5];
    const ull* src = part_keys + (size_t)b * NCAND;
    for (int i = tid; i < NCAND; i += BLK) buf[i] = src[i];
    if (tid < 128) sel[tid] = 0ULL;   // slots 100..127 stay 0 for the sort
    __syncthreads();

    select_topk(buf, NCAND, sel, hist, tie, wtot, selsh);

    bitonic_sort_desc<128>(sel);   // has leading __syncthreads

    for (int i = tid; i < K_; i += BLK) {
        const ull key = sel[i];
        const unsigned tiek = ~(unsigned)(key & 0xFFFFFFFFULL);
        DetRec d;
        d.score = __uint_as_float((unsigned)(key >> 32));
        d.cls   = (int)((tiek >> 18) & 3u);
        d.hw    = tiek & 0x3FFFFu;          // >= HW_ only for pad keys (score 0)
        dets[(size_t)b * K_ + i] = d;
    }
}

// ---------------------------------------------------------------------------
// Kernel 3: per-detection geometry (3200 threads).
// ---------------------------------------------------------------------------
__global__ void __launch_bounds__(BLK) geom_kernel(
        const DetRec* __restrict__ dets, const float* __restrict__ reg,
        const float* __restrict__ trans, const float* __restrict__ Km,
        const float* __restrict__ sz, const float* __restrict__ hcam,
        const float* __restrict__ dimen, float* __restrict__ out) {
    const int n = blockIdx.x * blockDim.x + threadIdx.x;
    if (n >= B_ * K_) return;
    const int b = n / K_;
    DetRec d = dets[n];
    const float score = d.score;
    const float clsf = (float)d.cls;
    unsigned hw = d.hw; if (hw >= HW_) hw = 0;  // pad entries: score==0, row zeroed
    const float xs = (float)(hw % W_);
    const float ys = (float)(hw / W_);

    const float* rg = reg + (size_t)b * 4 * HW_;
    const float delta = rg[hw];
    const float off_u = rg[HW_ + hw];
    const float ori0  = rg[2 * HW_ + hw];
    const float ori1  = rg[3 * HW_ + hw];

    const float* T = trans + b * 9;
    const float t00=T[0], t01=T[1], t02=T[2], t10=T[3], t11=T[4], t12=T[5],
                t20=T[6], t21=T[7], t22=T[8];
    const float det3 = t00*(t11*t22 - t12*t21) - t01*(t10*t22 - t12*t20)
                     + t02*(t10*t21 - t11*t20);
    const float idt = 1.0f / det3;
    const float i00 = (t11*t22 - t12*t21)*idt;
    const float i01 = (t02*t21 - t01*t22)*idt;
    const float i02 = (t01*t12 - t02*t11)*idt;

    const float pu = xs + off_u;
    const float img_x = i00*pu + i01*ys + i02;

    const float* Kb = Km + b * 9;
    const float k00=Kb[0],k01=Kb[1],k02=Kb[2],k10=Kb[3],k11=Kb[4],k12=Kb[5],
                k20=Kb[6],k21=Kb[7],k22=Kb[8];
    const float fx = k00, fy = k11, cx = k02;
    const float h = hcam[b];
    float d0 = dimen[b*3+0], d1 = dimen[b*3+1], d2 = dimen[b*3+2];
    if (!isfinite(d0)) d0 = 3.88f;
    if (!isfinite(d1)) d1 = 1.63f;
    if (!isfinite(d2)) d2 = 1.53f;

    const float h_ref = h - d1 * 0.5f;
    const float fyh = fy * fabsf(h_ref);
    const float log_dv_ref = logf(fmaxf(fyh, 1e-7f) / 28.01f);
    const float log_dv = fminf(fmaxf(log_dv_ref + delta, -4.0f), 8.0f);
    const float depth = fminf(fmaxf(fyh * expf(-log_dv), 0.5f), 120.0f);
    const float px = (img_x - cx) * depth / fx;

    const float PI_F  = 3.14159265358979323846f;
    const float ray = atanf(px / (depth + 1e-7f));
    float alpha = atanf(ori0 / (ori1 + 1e-7f));
    alpha += (ori1 >= 0.0f) ? -1.5707963267948966f : 1.5707963267948966f;
    float roty = alpha + ray;
    if (roty >  PI_F) roty -= 6.283185307179586f;
    if (roty < -PI_F) roty += 6.283185307179586f;

    const float cosr = cosf(roty), sinr = sinf(roty);
    const float cx8[8] = {-0.5f, 0.5f, 0.5f, 0.5f, 0.5f,-0.5f,-0.5f,-0.5f};
    const float cy8[8] = {-1.0f,-1.0f, 0.0f, 0.0f,-1.0f,-1.0f, 0.0f, 0.0f};
    const float cz8[8] = {-0.5f,-0.5f,-0.5f, 0.5f, 0.5f, 0.5f, 0.5f,-0.5f};
    float umin = 1e30f, umax = -1e30f, vmin = 1e30f, vmax = -1e30f;
    #pragma unroll
    for (int i = 0; i < 8; ++i) {
        const float xc = d0 * cx8[i];
        const float yc = d1 * cy8[i];
        const float zc = d2 * cz8[i];
        const float X = cosr*xc + sinr*zc + px;
        const float Y = yc + h;
        const float Z = -sinr*xc + cosr*zc + depth;
        const float w = k20*X + k21*Y + k22*Z;
        const float u = (k00*X + k01*Y + k02*Z) / w;
        const float v = (k10*X + k11*Y + k12*Z) / w;
        umin = fminf(umin, u); umax = fmaxf(umax, u);
        vmin = fminf(vmin, v); vmax = fmaxf(vmax, v);
    }
    const float img_w = sz[0], img_h = sz[1];
    const float xmin = fminf(fmaxf(umin, 0.0f), img_w);
    const float xmax = fminf(fmaxf(umax, 0.0f), img_w);
    const float ymin = fminf(fmaxf(vmin, 0.0f), img_h);
    const float ymax = fminf(fmaxf(vmax, 0.0f), img_h);

    const float keep = (score > 0.25f) ? 1.0f : 0.0f;
    float* o = out + (size_t)n * 14;
    o[0]  = clsf  * keep;
    o[1]  = alpha * keep;
    o[2]  = xmin  * keep;
    o[3]  = ymin  * keep;
    o[4]  = xmax  * keep;
    o[5]  = ymax  * keep;
    o[6]  = d1    * keep;   // pred_dims = roll(dims,-1)
    o[7]  = d2    * keep;
    o[8]  = d0    * keep;
    o[9]  = px    * keep;
    o[10] = h     * keep;
    o[11] = depth * keep;
    o[12] = roty  * keep;
    o[13] = score * keep;
}

extern "C" void kernel_launch(void* const* d_in, const int* in_sizes, int n_in,
                              void* d_out, int out_size, void* d_ws, size_t ws_size,
                              hipStream_t stream) {
    const float* heat  = (const float*)d_in[0];  // (32,3,256,832)
    const float* reg   = (const float*)d_in[1];  // (32,4,256,832)
    const float* trans = (const float*)d_in[2];  // (32,3,3)
    const float* Kmat  = (const float*)d_in[3];  // (32,3,3)
    const float* sz    = (const float*)d_in[4];  // (32,2)
    const float* hcam  = (const float*)d_in[5];  // (32,)
    const float* dimen = (const float*)d_in[6];  // (32,3)
    float* out = (float*)d_out;

    char* ws = (char*)d_ws;
    ull* part_keys = (ull*)ws;                                    // 1536*100*8 = 1,228,800 B
    ws += (size_t)B_ * C_ * PARTS * K_ * sizeof(ull);
    DetRec* dets = (DetRec*)ws;                                   // 3200*12 = 38,400 B

    topk_part_kernel<<<B_ * C_ * PARTS, BLK, 0, stream>>>(heat, part_keys);
    merge_kernel<<<B_, BLK, 0, stream>>>(part_keys, dets);
    geom_kernel<<<(B_ * K_ + BLK - 1) / BLK, BLK, 0, stream>>>(
        dets, reg, trans, Kmat, sz, hcam, dimen, out);
}

// Round 3
// 241.393 us; speedup vs baseline: 20.0491x; 1.0151x over previous
//
#include <hip/hip_runtime.h>
#include <math.h>

#define B_ 32
#define C_ 3
#define H_ 256
#define W_ 832
#define HW_ (H_*W_)
#define K_ 100
#define RPB 16                  // rows per block
#define PARTS (H_/RPB)          // 16 parts per channel
#define NLOAD (W_/4)            // 208 threads carry pixels
#define BLK 256
#define CAP 2048
#define NCAND (C_*PARTS*K_)     // 4800 candidates per batch
#define NB 2048                 // radix digit bins (11 bits)
#define TIE_CAP 128
#define SEL_PASSES 6

typedef unsigned long long ull;

// Descending bitonic sort of N (power of two) 64-bit keys in LDS (small N only).
template<int N>
__device__ inline void bitonic_sort_desc(ull* s) {
    for (int k = 2; k <= N; k <<= 1) {
        for (int j = k >> 1; j > 0; j >>= 1) {
            __syncthreads();
            for (int i = threadIdx.x; i < N; i += BLK) {
                int ixj = i ^ j;
                if (ixj > i) {
                    ull a = s[i], b = s[ixj];
                    bool up = ((i & k) == 0);
                    if (up ? (a < b) : (a > b)) { s[i] = b; s[ixj] = a; }
                }
            }
        }
    }
    __syncthreads();
}

// Given hist[NB] (digit counts, group total >= kneed), find digit d where the
// suffix count crosses kneed. Shuffle-based suffix scan, 2 barriers.
__device__ inline void find_digit(const unsigned* __restrict__ hist,
                                  unsigned* __restrict__ wtot,
                                  const int kneed,
                                  int* __restrict__ d_s,
                                  int* __restrict__ krem_s,
                                  int* __restrict__ m_s) {
    const int tid = threadIdx.x;
    const int lane = tid & 63;
    const int wid = tid >> 6;
    unsigned l[8];
    unsigned Ls = 0;
    #pragma unroll
    for (int j = 0; j < 8; ++j) { l[j] = hist[tid * 8 + j]; Ls += l[j]; }
    unsigned x = Ls;
    #pragma unroll
    for (int off = 1; off < 64; off <<= 1) {
        unsigned y = __shfl_down(x, off);
        if (lane + off < 64) x += y;
    }
    if (lane == 0) wtot[wid] = x;   // wave totals
    __syncthreads();
    unsigned tail = 0;
    #pragma unroll
    for (int w = 0; w < 4; ++w) if (w > wid) tail += wtot[w];
    unsigned s = x - Ls + tail;     // count of keys strictly above this range
    #pragma unroll
    for (int j = 7; j >= 0; --j) {
        const unsigned Sj = s + l[j];
        if (Sj >= (unsigned)kneed && s < (unsigned)kneed) {  // unique thread
            *d_s = tid * 8 + j;
            *krem_s = kneed - (int)s;
            *m_s = (int)l[j];
        }
        s = Sj;
    }
    __syncthreads();
}

// ---------------------------------------------------------------------------
// Exact top-K_ select from buf[0..cnt) (cnt >= K_) into dst[0..K_) (unsorted).
// MSB-first 2048-way radix over the 64-bit key with early exit to an exact
// O(m^2) tie rank once the threshold group fits TIE_CAP. Distribution-robust.
// sh: int[5] shared scratch {ocnt, tcnt, d, krem, m}.
// ---------------------------------------------------------------------------
__device__ inline void select_topk(const ull* __restrict__ buf, const int cnt,
                                   ull* __restrict__ dst,
                                   unsigned* __restrict__ hist,
                                   ull* __restrict__ tie,
                                   unsigned* __restrict__ wtot,
                                   int* __restrict__ sh) {
    const int tid = threadIdx.x;
    if (tid == 0) sh[0] = 0;                 // ocnt (published by pass-0 barriers)
    int kneed = K_;
    int pshift = 0;                          // valid for pass > 0
    ull prefix = 0;
    for (int pass = 0; pass < SEL_PASSES; ++pass) {
        const int rs = 53 - 11 * pass;
        const int shift = (rs > 0) ? rs : 0;
        #pragma unroll
        for (int j = 0; j < NB / BLK; ++j) hist[tid + j * BLK] = 0u;
        if (tid == 0) sh[1] = 0;             // tcnt
        __syncthreads();
        for (int i = tid; i < cnt; i += BLK) {
            const ull key = buf[i];
            if (pass > 0 && (key >> pshift) != prefix) continue;
            atomicAdd(&hist[(unsigned)(key >> shift) & 2047u], 1u);
        }
        __syncthreads();
        find_digit(hist, wtot, kneed, &sh[2], &sh[3], &sh[4]);
        const int d = sh[2], krem = sh[3], m = sh[4];
        const bool last = (m <= TIE_CAP) || (pass == SEL_PASSES - 1);
        for (int i = tid; i < cnt; i += BLK) {
            const ull key = buf[i];
            if (pass > 0 && (key >> pshift) != prefix) continue;
            const int dg = (int)((unsigned)(key >> shift) & 2047u);
            if (dg > d) {
                dst[atomicAdd(&sh[0], 1)] = key;
            } else if (last && dg == d) {
                const int p = atomicAdd(&sh[1], 1);
                if (p < TIE_CAP) tie[p] = key;
            }
        }
        __syncthreads();
        if (last) {
            const int n1 = K_ - krem;
            if (sh[1] <= TIE_CAP) {
                const int mm = sh[1];
                for (int i = tid; i < mm; i += BLK) {
                    const ull key = tie[i];
                    int r = 0;
                    for (int j = 0; j < mm; ++j) r += (tie[j] > key) ? 1 : 0;
                    if (r < krem) dst[n1 + r] = key;   // distinct keys -> unique ranks
                }
            } else {
                // >TIE_CAP keys identical in all 64 bits: only pad keys; copies
                for (int i = tid; i < krem; i += BLK) dst[n1 + i] = tie[0];
            }
            __syncthreads();
            return;
        }
        prefix = (prefix << 11) | (ull)(unsigned)d;
        pshift = shift;
        kneed = krem;
    }
}

// ---------------------------------------------------------------------------
// Kernel 1: separable 3x3 peak detect + exact top-100 per (channel, 16-row
// part). key = (value_bits<<32) | ~((c<<18)|pixel): unified comparator
// (score desc, channel asc, pixel asc) == composed jax two-stage top_k.
// Row loop is BARRIER-FREE: column-max neighbor exchange via intra-wave
// shuffles; the 6 wave-boundary threads (lanes 0/63 of interior waves) track
// the adjacent halo column in rolling scalar registers (1 extra scalar load
// per row). Waves run fully independently until the single pre-select barrier.
// Output: unsorted top-100 set.
// ---------------------------------------------------------------------------
__global__ void __launch_bounds__(BLK) topk_part_kernel(
        const float* __restrict__ heat, ull* __restrict__ part_out) {
    const int chan = blockIdx.x / PARTS;   // b*C + c
    const int c    = chan % C_;
    const int part = blockIdx.x % PARTS;
    const float* __restrict__ hp = heat + (size_t)chan * HW_;
    const int r0 = part * RPB;
    const int tid = threadIdx.x;
    const bool active = tid < NLOAD;
    const int x4 = tid * 4;
    const int lane = tid & 63;

    __shared__ unsigned hist[NB];
    __shared__ ull buf[CAP];
    __shared__ ull tie[TIE_CAP];
    __shared__ unsigned wtot[4];
    __shared__ int cnt;
    __shared__ int selsh[5];
    if (tid == 0) cnt = 0;

    // halo-column tracking: left halo col x4-1 for lane-0 threads (except
    // tid 0), right halo col x4+4 for lane-63 threads (tid 207's right
    // neighbor is the image edge -> -inf, no tracking needed)
    const bool needL = active && (lane == 0) && (tid > 0);
    const bool needR = active && (lane == 63);

    float4 rA, rB, rC, rD;
    float aL = 0.f, bL = 0.f, cL = 0.f, dL = 0.f;
    float aR = 0.f, bR = 0.f, cR = 0.f, dR = 0.f;
    {
        const int ym1 = (r0 == 0) ? 0 : r0 - 1;
        const int yp1 = (r0 == H_ - 1) ? r0 : r0 + 1;
        if (active) {
            rA = reinterpret_cast<const float4*>(hp + (size_t)ym1 * W_)[tid];
            rB = reinterpret_cast<const float4*>(hp + (size_t)r0  * W_)[tid];
            rC = reinterpret_cast<const float4*>(hp + (size_t)yp1 * W_)[tid];
        }
        if (needL) {
            aL = hp[(size_t)ym1 * W_ + x4 - 1];
            bL = hp[(size_t)r0  * W_ + x4 - 1];
            cL = hp[(size_t)yp1 * W_ + x4 - 1];
        }
        if (needR) {
            aR = hp[(size_t)ym1 * W_ + x4 + 4];
            bR = hp[(size_t)r0  * W_ + x4 + 4];
            cR = hp[(size_t)yp1 * W_ + x4 + 4];
        }
    }
    __syncthreads();   // cnt=0 visible before any append

    if (active) {
        for (int r = 0; r < RPB; ++r) {
            const int y = r0 + r;
            const int yn = (y + 2 > H_ - 1) ? H_ - 1 : y + 2;
            // prefetch row y+2 (clamped) — overlaps with this row's compute
            rD = reinterpret_cast<const float4*>(hp + (size_t)yn * W_)[tid];
            if (needL) dL = hp[(size_t)yn * W_ + x4 - 1];
            if (needR) dR = hp[(size_t)yn * W_ + x4 + 4];

            float4 vm;
            vm.x = fmaxf(fmaxf(rA.x, rB.x), rC.x);
            vm.y = fmaxf(fmaxf(rA.y, rB.y), rC.y);
            vm.z = fmaxf(fmaxf(rA.z, rB.z), rC.z);
            vm.w = fmaxf(fmaxf(rA.w, rB.w), rC.w);
            const float lmax = needL ? fmaxf(fmaxf(aL, bL), cL) : -INFINITY;
            const float rmax = needR ? fmaxf(fmaxf(aR, bR), cR) : -INFINITY;

            // intra-wave neighbor exchange (no LDS, no barrier)
            float left  = __shfl_up(vm.w, 1);
            float right = __shfl_down(vm.x, 1);
            if (lane == 0) left = lmax;                    // tid 0 -> -inf
            if (lane == 63 || tid == NLOAD - 1) right = rmax;  // tid 207 -> -inf

            const float vn[6] = {left, vm.x, vm.y, vm.z, vm.w, right};
            const float vv[4] = {rB.x, rB.y, rB.z, rB.w};
            #pragma unroll
            for (int i = 0; i < 4; ++i) {
                const float v = vv[i];
                const bool peak = (v >= vn[i]) && (v >= vn[i+1]) && (v >= vn[i+2]);
                const ull m = __ballot(peak);
                if (peak) {
                    const unsigned p = (unsigned)(y * W_ + x4 + i);
                    const unsigned tiek = ((unsigned)c << 18) | p;
                    const ull key = ((ull)__float_as_uint(v) << 32) | (ull)(~tiek);
                    const int rank = __popcll(m & ((1ULL << lane) - 1ULL));
                    const int leader = __ffsll((long long)m) - 1;
                    int base = 0;
                    if (lane == leader) base = atomicAdd(&cnt, (int)__popcll(m));
                    base = __shfl(base, leader);
                    const int pos = base + rank;
                    if (pos < CAP) buf[pos] = key;
                }
            }
            rA = rB; rB = rC; rC = rD;
            aL = bL; bL = cL; cL = dL;
            aR = bR; bR = cR; cR = dR;
        }
    }
    __syncthreads();   // cnt + buf final

    const int cc = (cnt < CAP) ? cnt : CAP;
    ull* o = part_out + (size_t)blockIdx.x * K_;

    if (cc <= K_) {    // uniform branch — fewer candidates than K: emit all
        for (int i = tid; i < cc; i += BLK) o[i] = buf[i];
        for (int i = cc + tid; i < K_; i += BLK) o[i] = 0ULL;
        return;
    }

    select_topk(buf, cc, o, hist, tie, wtot, selsh);
}

// ---------------------------------------------------------------------------
// Kernel 2 (fused merge+geom): per-batch top-100 of 48x100 candidates
// (radix-with-early-exit select), tiny sort-128, then per-detection geometry
// straight out of LDS — saves a launch and the dets global round-trip.
// ---------------------------------------------------------------------------
__global__ void __launch_bounds__(BLK) merge_geom_kernel(
        const ull* __restrict__ part_keys, const float* __restrict__ reg,
        const float* __restrict__ trans, const float* __restrict__ Km,
        const float* __restrict__ sz, const float* __restrict__ hcam,
        const float* __restrict__ dimen, float* __restrict__ out) {
    const int b = blockIdx.x;
    const int tid = threadIdx.x;
    __shared__ ull buf[NCAND];
    __shared__ unsigned hist[NB];
    __shared__ ull sel[128];
    __shared__ ull tie[TIE_CAP];
    __shared__ unsigned wtot[4];
    __shared__ int selsh[5];
    const ull* src = part_keys + (size_t)b * NCAND;
    for (int i = tid; i < NCAND; i += BLK) buf[i] = src[i];
    if (tid < 128) sel[tid] = 0ULL;   // slots 100..127 stay 0 for the sort
    __syncthreads();

    select_topk(buf, NCAND, sel, hist, tie, wtot, selsh);

    bitonic_sort_desc<128>(sel);   // has leading __syncthreads

    // ---- geometry, one thread per detection (tid < 100) ----
    for (int i = tid; i < K_; i += BLK) {
        const ull key = sel[i];
        const unsigned tiek = ~(unsigned)(key & 0xFFFFFFFFULL);
        const float score = __uint_as_float((unsigned)(key >> 32));
        const float clsf = (float)((tiek >> 18) & 3u);
        unsigned hw = tiek & 0x3FFFFu;
        if (hw >= HW_) hw = 0;   // pad entries: score==0, row zeroed below
        const float xs = (float)(hw % W_);
        const float ys = (float)(hw / W_);

        const float* rg = reg + (size_t)b * 4 * HW_;
        const float delta = rg[hw];
        const float off_u = rg[HW_ + hw];
        const float ori0  = rg[2 * HW_ + hw];
        const float ori1  = rg[3 * HW_ + hw];

        const float* T = trans + b * 9;
        const float t00=T[0], t01=T[1], t02=T[2], t10=T[3], t11=T[4], t12=T[5],
                    t20=T[6], t21=T[7], t22=T[8];
        const float det3 = t00*(t11*t22 - t12*t21) - t01*(t10*t22 - t12*t20)
                         + t02*(t10*t21 - t11*t20);
        const float idt = 1.0f / det3;
        const float i00 = (t11*t22 - t12*t21)*idt;
        const float i01 = (t02*t21 - t01*t22)*idt;
        const float i02 = (t01*t12 - t02*t11)*idt;

        const float pu = xs + off_u;
        const float img_x = i00*pu + i01*ys + i02;

        const float* Kb = Km + b * 9;
        const float k00=Kb[0],k01=Kb[1],k02=Kb[2],k10=Kb[3],k11=Kb[4],k12=Kb[5],
                    k20=Kb[6],k21=Kb[7],k22=Kb[8];
        const float fx = k00, fy = k11, cx = k02;
        const float h = hcam[b];
        float d0 = dimen[b*3+0], d1 = dimen[b*3+1], d2 = dimen[b*3+2];
        if (!isfinite(d0)) d0 = 3.88f;
        if (!isfinite(d1)) d1 = 1.63f;
        if (!isfinite(d2)) d2 = 1.53f;

        const float h_ref = h - d1 * 0.5f;
        const float fyh = fy * fabsf(h_ref);
        const float log_dv_ref = logf(fmaxf(fyh, 1e-7f) / 28.01f);
        const float log_dv = fminf(fmaxf(log_dv_ref + delta, -4.0f), 8.0f);
        const float depth = fminf(fmaxf(fyh * expf(-log_dv), 0.5f), 120.0f);
        const float px = (img_x - cx) * depth / fx;

        const float PI_F  = 3.14159265358979323846f;
        const float ray = atanf(px / (depth + 1e-7f));
        float alpha = atanf(ori0 / (ori1 + 1e-7f));
        alpha += (ori1 >= 0.0f) ? -1.5707963267948966f : 1.5707963267948966f;
        float roty = alpha + ray;
        if (roty >  PI_F) roty -= 6.283185307179586f;
        if (roty < -PI_F) roty += 6.283185307179586f;

        const float cosr = cosf(roty), sinr = sinf(roty);
        const float cx8[8] = {-0.5f, 0.5f, 0.5f, 0.5f, 0.5f,-0.5f,-0.5f,-0.5f};
        const float cy8[8] = {-1.0f,-1.0f, 0.0f, 0.0f,-1.0f,-1.0f, 0.0f, 0.0f};
        const float cz8[8] = {-0.5f,-0.5f,-0.5f, 0.5f, 0.5f, 0.5f, 0.5f,-0.5f};
        float umin = 1e30f, umax = -1e30f, vmin = 1e30f, vmax = -1e30f;
        #pragma unroll
        for (int j = 0; j < 8; ++j) {
            const float xc = d0 * cx8[j];
            const float yc = d1 * cy8[j];
            const float zc = d2 * cz8[j];
            const float X = cosr*xc + sinr*zc + px;
            const float Y = yc + h;
            const float Z = -sinr*xc + cosr*zc + depth;
            const float w = k20*X + k21*Y + k22*Z;
            const float u = (k00*X + k01*Y + k02*Z) / w;
            const float v = (k10*X + k11*Y + k12*Z) / w;
            umin = fminf(umin, u); umax = fmaxf(umax, u);
            vmin = fminf(vmin, v); vmax = fmaxf(vmax, v);
        }
        const float img_w = sz[0], img_h = sz[1];
        const float xmin = fminf(fmaxf(umin, 0.0f), img_w);
        const float xmax = fminf(fmaxf(umax, 0.0f), img_w);
        const float ymin = fminf(fmaxf(vmin, 0.0f), img_h);
        const float ymax = fminf(fmaxf(vmax, 0.0f), img_h);

        const float keep = (score > 0.25f) ? 1.0f : 0.0f;
        float* o = out + (size_t)(b * K_ + i) * 14;
        o[0]  = clsf  * keep;
        o[1]  = alpha * keep;
        o[2]  = xmin  * keep;
        o[3]  = ymin  * keep;
        o[4]  = xmax  * keep;
        o[5]  = ymax  * keep;
        o[6]  = d1    * keep;   // pred_dims = roll(dims,-1)
        o[7]  = d2    * keep;
        o[8]  = d0    * keep;
        o[9]  = px    * keep;
        o[10] = h     * keep;
        o[11] = depth * keep;
        o[12] = roty  * keep;
        o[13] = score * keep;
    }
}

extern "C" void kernel_launch(void* const* d_in, const int* in_sizes, int n_in,
                              void* d_out, int out_size, void* d_ws, size_t ws_size,
                              hipStream_t stream) {
    const float* heat  = (const float*)d_in[0];  // (32,3,256,832)
    const float* reg   = (const float*)d_in[1];  // (32,4,256,832)
    const float* trans = (const float*)d_in[2];  // (32,3,3)
    const float* Kmat  = (const float*)d_in[3];  // (32,3,3)
    const float* sz    = (const float*)d_in[4];  // (32,2)
    const float* hcam  = (const float*)d_in[5];  // (32,)
    const float* dimen = (const float*)d_in[6];  // (32,3)
    float* out = (float*)d_out;

    ull* part_keys = (ull*)d_ws;                 // 1536*100*8 = 1,228,800 B

    topk_part_kernel<<<B_ * C_ * PARTS, BLK, 0, stream>>>(heat, part_keys);
    merge_geom_kernel<<<B_, BLK, 0, stream>>>(
        part_keys, reg, trans, Kmat, sz, hcam, dimen, out);
}

// Round 4
// 239.869 us; speedup vs baseline: 20.1765x; 1.0064x over previous
//
#include <hip/hip_runtime.h>
#include <math.h>

#define B_ 32
#define C_ 3
#define H_ 256
#define W_ 832
#define HW_ (H_*W_)
#define NQ (W_/4)               // 208 quads (float4 columns) per row
#define K_ 100
#define RPB 16                  // rows per block
#define PARTS (H_/RPB)          // 16 parts per channel
#define BLK 256
#define CAP 2048
#define NCAND (C_*PARTS*K_)     // 4800 candidates per batch
#define NB 2048                 // radix digit bins (11 bits)
#define TIE_CAP 128
#define SEL_PASSES 6
#define QPW 62                  // emitting quads per wave (overlapped mapping)

typedef unsigned long long ull;

// Descending bitonic sort of N (power of two) 64-bit keys in LDS (small N only).
template<int N>
__device__ inline void bitonic_sort_desc(ull* s) {
    for (int k = 2; k <= N; k <<= 1) {
        for (int j = k >> 1; j > 0; j >>= 1) {
            __syncthreads();
            for (int i = threadIdx.x; i < N; i += BLK) {
                int ixj = i ^ j;
                if (ixj > i) {
                    ull a = s[i], b = s[ixj];
                    bool up = ((i & k) == 0);
                    if (up ? (a < b) : (a > b)) { s[i] = b; s[ixj] = a; }
                }
            }
        }
    }
    __syncthreads();
}

// Given hist[NB] (digit counts, group total >= kneed), find digit d where the
// suffix count crosses kneed. Shuffle-based suffix scan, 2 barriers.
__device__ inline void find_digit(const unsigned* __restrict__ hist,
                                  unsigned* __restrict__ wtot,
                                  const int kneed,
                                  int* __restrict__ d_s,
                                  int* __restrict__ krem_s,
                                  int* __restrict__ m_s) {
    const int tid = threadIdx.x;
    const int lane = tid & 63;
    const int wid = tid >> 6;
    unsigned l[8];
    unsigned Ls = 0;
    #pragma unroll
    for (int j = 0; j < 8; ++j) { l[j] = hist[tid * 8 + j]; Ls += l[j]; }
    unsigned x = Ls;
    #pragma unroll
    for (int off = 1; off < 64; off <<= 1) {
        unsigned y = __shfl_down(x, off);
        if (lane + off < 64) x += y;
    }
    if (lane == 0) wtot[wid] = x;   // wave totals
    __syncthreads();
    unsigned tail = 0;
    #pragma unroll
    for (int w = 0; w < 4; ++w) if (w > wid) tail += wtot[w];
    unsigned s = x - Ls + tail;     // count of keys strictly above this range
    #pragma unroll
    for (int j = 7; j >= 0; --j) {
        const unsigned Sj = s + l[j];
        if (Sj >= (unsigned)kneed && s < (unsigned)kneed) {  // unique thread
            *d_s = tid * 8 + j;
            *krem_s = kneed - (int)s;
            *m_s = (int)l[j];
        }
        s = Sj;
    }
    __syncthreads();
}

// ---------------------------------------------------------------------------
// Exact top-K_ select from buf[0..cnt) (cnt >= K_) into dst[0..K_) (unsorted).
// MSB-first 2048-way radix over the 64-bit key with early exit to an exact
// O(m^2) tie rank once the threshold group fits TIE_CAP. Pass 0 uses a
// wave-aggregated histogram (leader loop over distinct digits) because the
// score distribution concentrates ~all keys into a handful of top-bit bins,
// which would serialize same-address LDS atomics ~64 deep; later passes have
// spread digits and use direct atomics. sh: int[5] {ocnt, tcnt, d, krem, m}.
// ---------------------------------------------------------------------------
__device__ inline void select_topk(const ull* __restrict__ buf, const int cnt,
                                   ull* __restrict__ dst,
                                   unsigned* __restrict__ hist,
                                   ull* __restrict__ tie,
                                   unsigned* __restrict__ wtot,
                                   int* __restrict__ sh) {
    const int tid = threadIdx.x;
    const int lane = tid & 63;
    if (tid == 0) sh[0] = 0;                 // ocnt (published by pass-0 barriers)
    int kneed = K_;
    int pshift = 0;                          // valid for pass > 0
    ull prefix = 0;
    for (int pass = 0; pass < SEL_PASSES; ++pass) {
        const int rs = 53 - 11 * pass;
        const int shift = (rs > 0) ? rs : 0;
        #pragma unroll
        for (int j = 0; j < NB / BLK; ++j) hist[tid + j * BLK] = 0u;
        if (tid == 0) sh[1] = 0;             // tcnt
        __syncthreads();
        if (pass == 0) {
            // wave-aggregated histogram: one atomic per distinct digit per wave
            for (int i = tid; i < cnt; i += BLK) {
                const unsigned dg = (unsigned)(buf[i] >> shift) & 2047u;
                ull unclaimed = __ballot(1);
                while (unclaimed) {
                    const int leader = __ffsll((long long)unclaimed) - 1;
                    const unsigned ldg = __shfl(dg, leader);
                    const ull same = __ballot(dg == ldg);
                    if (lane == leader)
                        atomicAdd(&hist[ldg], (unsigned)__popcll(same));
                    unclaimed &= ~same;
                }
            }
        } else {
            for (int i = tid; i < cnt; i += BLK) {
                const ull key = buf[i];
                if ((key >> pshift) != prefix) continue;
                atomicAdd(&hist[(unsigned)(key >> shift) & 2047u], 1u);
            }
        }
        __syncthreads();
        find_digit(hist, wtot, kneed, &sh[2], &sh[3], &sh[4]);
        const int d = sh[2], krem = sh[3], m = sh[4];
        const bool last = (m <= TIE_CAP) || (pass == SEL_PASSES - 1);
        for (int i = tid; i < cnt; i += BLK) {
            const ull key = buf[i];
            if (pass > 0 && (key >> pshift) != prefix) continue;
            const int dg = (int)((unsigned)(key >> shift) & 2047u);
            if (dg > d) {
                dst[atomicAdd(&sh[0], 1)] = key;
            } else if (last && dg == d) {
                const int p = atomicAdd(&sh[1], 1);
                if (p < TIE_CAP) tie[p] = key;
            }
        }
        __syncthreads();
        if (last) {
            const int n1 = K_ - krem;
            if (sh[1] <= TIE_CAP) {
                const int mm = sh[1];
                for (int i = tid; i < mm; i += BLK) {
                    const ull key = tie[i];
                    int r = 0;
                    for (int j = 0; j < mm; ++j) r += (tie[j] > key) ? 1 : 0;
                    if (r < krem) dst[n1 + r] = key;   // distinct keys -> unique ranks
                }
            } else {
                // >TIE_CAP keys identical in all 64 bits: only pad keys; copies
                for (int i = tid; i < krem; i += BLK) dst[n1 + i] = tie[0];
            }
            __syncthreads();
            return;
        }
        prefix = (prefix << 11) | (ull)(unsigned)d;
        pshift = shift;
        kneed = krem;
    }
}

// ---------------------------------------------------------------------------
// Kernel 1: separable 3x3 peak detect + exact top-100 per (channel, 16-row
// part). key = (value_bits<<32) | ~((c<<18)|pixel): unified comparator
// (score desc, channel asc, pixel asc) == composed jax two-stage top_k.
//
// Row loop structure:
//  - overlapped-wave column mapping: wave w, lane l covers quad q = 62w+l-1;
//    lanes 0/63 are halo-only, lanes 1..62 emit. All 256 lanes active, fully
//    coalesced, zero cross-wave traffic, zero barriers, no scalar halo loads.
//    Out-of-image lanes force their column-max to -inf (== SAME pad for max).
//  - 6-row rolling register window, prefetch issued 5 rows ahead (load->use
//    slack = 4 iterations) to cover post-fill cold-HBM latency. Fully
//    unrolled so the window stays in registers (static indices).
//  - one shared-atomic append per row per wave (offsets from the 4 ballots).
// Output: unsorted top-100 set per part.
// ---------------------------------------------------------------------------
__global__ void __launch_bounds__(BLK) topk_part_kernel(
        const float* __restrict__ heat, ull* __restrict__ part_out) {
    const int chan = blockIdx.x / PARTS;   // b*C + c
    const int c    = chan % C_;
    const int part = blockIdx.x % PARTS;
    const float* __restrict__ hp = heat + (size_t)chan * HW_;
    const int r0 = part * RPB;
    const int tid = threadIdx.x;
    const int lane = tid & 63;
    const int wid = tid >> 6;

    const int q = QPW * wid + lane - 1;          // quad this lane carries
    const bool ghost = (q < 0) || (q >= NQ);     // outside image -> -inf colmax
    const int qc = (q < 0) ? 0 : ((q >= NQ) ? NQ - 1 : q);
    const bool emitter = (lane >= 1) && (lane <= QPW) && !ghost;

    __shared__ unsigned hist[NB];
    __shared__ ull buf[CAP];
    __shared__ ull tie[TIE_CAP];
    __shared__ unsigned wtot[4];
    __shared__ int cnt;
    __shared__ int selsh[5];
    if (tid == 0) cnt = 0;

    float4 R[6];
    #pragma unroll
    for (int j = 0; j < 6; ++j) {
        int row = r0 - 1 + j;
        row = (row < 0) ? 0 : ((row > H_ - 1) ? H_ - 1 : row);
        R[j] = reinterpret_cast<const float4*>(hp + (size_t)row * W_)[qc];
    }
    __syncthreads();   // cnt=0 visible before any append

    #pragma unroll
    for (int r = 0; r < RPB; ++r) {
        const int y = r0 + r;
        const float4 ra = R[r % 6];
        const float4 rb = R[(r + 1) % 6];
        const float4 rc = R[(r + 2) % 6];
        if (r < RPB - 4) {   // rows r0+5 .. r0+16; beyond that nothing is needed
            const int yn = (y + 5 > H_ - 1) ? H_ - 1 : y + 5;
            R[r % 6] = reinterpret_cast<const float4*>(hp + (size_t)yn * W_)[qc];
        }

        float4 vm;
        vm.x = fmaxf(fmaxf(ra.x, rb.x), rc.x);
        vm.y = fmaxf(fmaxf(ra.y, rb.y), rc.y);
        vm.z = fmaxf(fmaxf(ra.z, rb.z), rc.z);
        vm.w = fmaxf(fmaxf(ra.w, rb.w), rc.w);
        if (ghost) { vm.x = vm.y = vm.z = vm.w = -INFINITY; }

        const float left  = __shfl_up(vm.w, 1);   // lane-1's colmax (halo ok)
        const float right = __shfl_down(vm.x, 1); // lane+1's colmax

        const float vn[6] = {left, vm.x, vm.y, vm.z, vm.w, right};
        const float vv[4] = {rb.x, rb.y, rb.z, rb.w};
        ull m[4];
        bool pk[4];
        #pragma unroll
        for (int i = 0; i < 4; ++i) {
            pk[i] = emitter && (vv[i] >= vn[i]) && (vv[i] >= vn[i+1]) && (vv[i] >= vn[i+2]);
            m[i] = __ballot(pk[i]);
        }
        const int tot = (int)(__popcll(m[0]) + __popcll(m[1]) +
                              __popcll(m[2]) + __popcll(m[3]));
        if (tot) {           // wave-uniform
            int base = 0;
            if (lane == 0) base = atomicAdd(&cnt, tot);
            base = __shfl(base, 0);
            int off = 0;
            #pragma unroll
            for (int i = 0; i < 4; ++i) {
                if (pk[i]) {
                    const unsigned p = (unsigned)(y * W_ + q * 4 + i);
                    const unsigned tiek = ((unsigned)c << 18) | p;
                    const ull key = ((ull)__float_as_uint(vv[i]) << 32) | (ull)(~tiek);
                    const int rank = (int)__popcll(m[i] & ((1ULL << lane) - 1ULL));
                    const int pos = base + off + rank;
                    if (pos < CAP) buf[pos] = key;
                }
                off += (int)__popcll(m[i]);
            }
        }
    }
    __syncthreads();   // cnt + buf final

    const int cc = (cnt < CAP) ? cnt : CAP;
    ull* o = part_out + (size_t)blockIdx.x * K_;

    if (cc <= K_) {    // uniform branch — fewer candidates than K: emit all
        for (int i = tid; i < cc; i += BLK) o[i] = buf[i];
        for (int i = cc + tid; i < K_; i += BLK) o[i] = 0ULL;
        return;
    }

    select_topk(buf, cc, o, hist, tie, wtot, selsh);
}

// ---------------------------------------------------------------------------
// Kernel 2 (fused merge+geom): per-batch top-100 of 48x100 candidates
// (radix-with-early-exit select), tiny sort-128, then per-detection geometry
// straight out of LDS.
// ---------------------------------------------------------------------------
__global__ void __launch_bounds__(BLK) merge_geom_kernel(
        const ull* __restrict__ part_keys, const float* __restrict__ reg,
        const float* __restrict__ trans, const float* __restrict__ Km,
        const float* __restrict__ sz, const float* __restrict__ hcam,
        const float* __restrict__ dimen, float* __restrict__ out) {
    const int b = blockIdx.x;
    const int tid = threadIdx.x;
    __shared__ ull buf[NCAND];
    __shared__ unsigned hist[NB];
    __shared__ ull sel[128];
    __shared__ ull tie[TIE_CAP];
    __shared__ unsigned wtot[4];
    __shared__ int selsh[5];
    const ull* src = part_keys + (size_t)b * NCAND;
    for (int i = tid; i < NCAND; i += BLK) buf[i] = src[i];
    if (tid < 128) sel[tid] = 0ULL;   // slots 100..127 stay 0 for the sort
    __syncthreads();

    select_topk(buf, NCAND, sel, hist, tie, wtot, selsh);

    bitonic_sort_desc<128>(sel);   // has leading __syncthreads

    // ---- geometry, one thread per detection ----
    for (int i = tid; i < K_; i += BLK) {
        const ull key = sel[i];
        const unsigned tiek = ~(unsigned)(key & 0xFFFFFFFFULL);
        const float score = __uint_as_float((unsigned)(key >> 32));
        const float clsf = (float)((tiek >> 18) & 3u);
        unsigned hw = tiek & 0x3FFFFu;
        if (hw >= HW_) hw = 0;   // pad entries: score==0, row zeroed below
        const float xs = (float)(hw % W_);
        const float ys = (float)(hw / W_);

        const float* rg = reg + (size_t)b * 4 * HW_;
        const float delta = rg[hw];
        const float off_u = rg[HW_ + hw];
        const float ori0  = rg[2 * HW_ + hw];
        const float ori1  = rg[3 * HW_ + hw];

        const float* T = trans + b * 9;
        const float t00=T[0], t01=T[1], t02=T[2], t10=T[3], t11=T[4], t12=T[5],
                    t20=T[6], t21=T[7], t22=T[8];
        const float det3 = t00*(t11*t22 - t12*t21) - t01*(t10*t22 - t12*t20)
                         + t02*(t10*t21 - t11*t20);
        const float idt = 1.0f / det3;
        const float i00 = (t11*t22 - t12*t21)*idt;
        const float i01 = (t02*t21 - t01*t22)*idt;
        const float i02 = (t01*t12 - t02*t11)*idt;

        const float pu = xs + off_u;
        const float img_x = i00*pu + i01*ys + i02;

        const float* Kb = Km + b * 9;
        const float k00=Kb[0],k01=Kb[1],k02=Kb[2],k10=Kb[3],k11=Kb[4],k12=Kb[5],
                    k20=Kb[6],k21=Kb[7],k22=Kb[8];
        const float fx = k00, fy = k11, cx = k02;
        const float h = hcam[b];
        float d0 = dimen[b*3+0], d1 = dimen[b*3+1], d2 = dimen[b*3+2];
        if (!isfinite(d0)) d0 = 3.88f;
        if (!isfinite(d1)) d1 = 1.63f;
        if (!isfinite(d2)) d2 = 1.53f;

        const float h_ref = h - d1 * 0.5f;
        const float fyh = fy * fabsf(h_ref);
        const float log_dv_ref = logf(fmaxf(fyh, 1e-7f) / 28.01f);
        const float log_dv = fminf(fmaxf(log_dv_ref + delta, -4.0f), 8.0f);
        const float depth = fminf(fmaxf(fyh * expf(-log_dv), 0.5f), 120.0f);
        const float px = (img_x - cx) * depth / fx;

        const float PI_F  = 3.14159265358979323846f;
        const float ray = atanf(px / (depth + 1e-7f));
        float alpha = atanf(ori0 / (ori1 + 1e-7f));
        alpha += (ori1 >= 0.0f) ? -1.5707963267948966f : 1.5707963267948966f;
        float roty = alpha + ray;
        if (roty >  PI_F) roty -= 6.283185307179586f;
        if (roty < -PI_F) roty += 6.283185307179586f;

        const float cosr = cosf(roty), sinr = sinf(roty);
        const float cx8[8] = {-0.5f, 0.5f, 0.5f, 0.5f, 0.5f,-0.5f,-0.5f,-0.5f};
        const float cy8[8] = {-1.0f,-1.0f, 0.0f, 0.0f,-1.0f,-1.0f, 0.0f, 0.0f};
        const float cz8[8] = {-0.5f,-0.5f,-0.5f, 0.5f, 0.5f, 0.5f, 0.5f,-0.5f};
        float umin = 1e30f, umax = -1e30f, vmin = 1e30f, vmax = -1e30f;
        #pragma unroll
        for (int j = 0; j < 8; ++j) {
            const float xc = d0 * cx8[j];
            const float yc = d1 * cy8[j];
            const float zc = d2 * cz8[j];
            const float X = cosr*xc + sinr*zc + px;
            const float Y = yc + h;
            const float Z = -sinr*xc + cosr*zc + depth;
            const float w = k20*X + k21*Y + k22*Z;
            const float u = (k00*X + k01*Y + k02*Z) / w;
            const float v = (k10*X + k11*Y + k12*Z) / w;
            umin = fminf(umin, u); umax = fmaxf(umax, u);
            vmin = fminf(vmin, v); vmax = fmaxf(vmax, v);
        }
        const float img_w = sz[0], img_h = sz[1];
        const float xmin = fminf(fmaxf(umin, 0.0f), img_w);
        const float xmax = fminf(fmaxf(umax, 0.0f), img_w);
        const float ymin = fminf(fmaxf(vmin, 0.0f), img_h);
        const float ymax = fminf(fmaxf(vmax, 0.0f), img_h);

        const float keep = (score > 0.25f) ? 1.0f : 0.0f;
        float* o = out + (size_t)(b * K_ + i) * 14;
        o[0]  = clsf  * keep;
        o[1]  = alpha * keep;
        o[2]  = xmin  * keep;
        o[3]  = ymin  * keep;
        o[4]  = xmax  * keep;
        o[5]  = ymax  * keep;
        o[6]  = d1    * keep;   // pred_dims = roll(dims,-1)
        o[7]  = d2    * keep;
        o[8]  = d0    * keep;
        o[9]  = px    * keep;
        o[10] = h     * keep;
        o[11] = depth * keep;
        o[12] = roty  * keep;
        o[13] = score * keep;
    }
}

extern "C" void kernel_launch(void* const* d_in, const int* in_sizes, int n_in,
                              void* d_out, int out_size, void* d_ws, size_t ws_size,
                              hipStream_t stream) {
    const float* heat  = (const float*)d_in[0];  // (32,3,256,832)
    const float* reg   = (const float*)d_in[1];  // (32,4,256,832)
    const float* trans = (const float*)d_in[2];  // (32,3,3)
    const float* Kmat  = (const float*)d_in[3];  // (32,3,3)
    const float* sz    = (const float*)d_in[4];  // (32,2)
    const float* hcam  = (const float*)d_in[5];  // (32,)
    const float* dimen = (const float*)d_in[6];  // (32,3)
    float* out = (float*)d_out;

    ull* part_keys = (ull*)d_ws;                 // 1536*100*8 = 1,228,800 B

    topk_part_kernel<<<B_ * C_ * PARTS, BLK, 0, stream>>>(heat, part_keys);
    merge_geom_kernel<<<B_, BLK, 0, stream>>>(
        part_keys, reg, trans, Kmat, sz, hcam, dimen, out);
}